// Round 1
// baseline (849.238 us; speedup 1.0000x reference)
//
#include <hip/hip_runtime.h>
#include <hip/hip_bf16.h>

// ---------------- CSR build ----------------
__global__ void k_hist(const int* __restrict__ dst, int* __restrict__ cnt, int E) {
    int e = blockIdx.x * 256 + threadIdx.x;
    if (e < E) atomicAdd(&cnt[dst[e]], 1);
}

__global__ __launch_bounds__(1024)
void k_scan(int* cntcur, int* rowptr, int N) {
    __shared__ int wsum[16];
    int tid = threadIdx.x;
    int per = (N + 1023) >> 10;
    int beg = tid * per;
    int end = beg + per; if (end > N) end = N;
    int sum = 0;
    if (beg < N) for (int i = beg; i < end; ++i) sum += cntcur[i];
    int lane = tid & 63, w = tid >> 6;
    int v = sum;
    for (int off = 1; off < 64; off <<= 1) {
        int t = __shfl_up(v, off);
        if (lane >= off) v += t;
    }
    if (lane == 63) wsum[w] = v;
    __syncthreads();
    if (tid < 64) {
        int t = (tid < 16) ? wsum[tid] : 0;
        for (int off = 1; off < 16; off <<= 1) {
            int u = __shfl_up(t, off);
            if (lane >= off) t += u;
        }
        if (tid < 16) wsum[tid] = t;
    }
    __syncthreads();
    int waveoff = (w == 0) ? 0 : wsum[w - 1];
    int excl = v + waveoff - sum;
    if (beg < N) {
        int run = excl;
        for (int i = beg; i < end; ++i) {
            int c = cntcur[i];
            rowptr[i] = run;
            cntcur[i] = run;   // becomes fill cursor
            run += c;
        }
        if (end == N) rowptr[N] = run;
    }
}

__global__ void k_fill(const int* __restrict__ src, const int* __restrict__ dst,
                       int* __restrict__ cursor, int* __restrict__ col, int E) {
    int e = blockIdx.x * 256 + threadIdx.x;
    if (e < E) {
        int p = atomicAdd(&cursor[dst[e]], 1);
        col[p] = src[e];
    }
}

__global__ void k_dinv(const int* __restrict__ rowptr, float* __restrict__ dinv, int N) {
    int v = blockIdx.x * 256 + threadIdx.x;
    if (v < N) {
        float deg = (float)(rowptr[v + 1] - rowptr[v]) + 1.0f;  // + self loop
        dinv[v] = 1.0f / sqrtf(deg);
    }
}

__global__ void k_copy(const float4* __restrict__ xi, const float4* __restrict__ si,
                       float4* __restrict__ xo, float4* __restrict__ so, int n4) {
    int i = blockIdx.x * 256 + threadIdx.x;
    if (i < n4) { xo[i] = xi[i]; so[i] = si[i]; }
}

// ---------------- aggregations (one wave per dst row, lane = feature) ----------------
__global__ __launch_bounds__(64)
void k_gin_agg(const float* __restrict__ x, const float* __restrict__ s,
               const int* __restrict__ rowptr, const int* __restrict__ col,
               float* __restrict__ agg, int N) {
    int v = blockIdx.x;
    if (v >= N) return;
    int d = threadIdx.x;
    size_t vd = (size_t)v * 64 + d;
    float ax = x[vd], as = s[vd];
    int k = rowptr[v], end = rowptr[v + 1];
    for (; k + 1 < end; k += 2) {
        int u0 = col[k], u1 = col[k + 1];
        ax += x[(size_t)u0 * 64 + d];
        as += s[(size_t)u0 * 64 + d];
        ax += x[(size_t)u1 * 64 + d];
        as += s[(size_t)u1 * 64 + d];
    }
    if (k < end) {
        int u = col[k];
        ax += x[(size_t)u * 64 + d];
        as += s[(size_t)u * 64 + d];
    }
    agg[(size_t)v * 128 + d] = ax;
    agg[(size_t)v * 128 + 64 + d] = as;
}

__global__ __launch_bounds__(64)
void k_gcn_agg(const float* __restrict__ sw, const float* __restrict__ dinv,
               const int* __restrict__ rowptr, const int* __restrict__ col,
               const float* __restrict__ bg, float* __restrict__ s_out, int N) {
    int v = blockIdx.x;
    if (v >= N) return;
    int d = threadIdx.x;
    float dv = dinv[v];
    float acc = dv * sw[(size_t)v * 64 + d];   // self-loop: dinv[v]^2 * sw[v] (dv factored out)
    int k = rowptr[v], end = rowptr[v + 1];
    for (; k + 1 < end; k += 2) {
        int u0 = col[k], u1 = col[k + 1];
        acc += dinv[u0] * sw[(size_t)u0 * 64 + d];
        acc += dinv[u1] * sw[(size_t)u1 * 64 + d];
    }
    if (k < end) {
        int u = col[k];
        acc += dinv[u] * sw[(size_t)u * 64 + d];
    }
    s_out[(size_t)v * 64 + d] = tanhf(dv * acc + bg[d]);
}

// ---------------- fused GIN MLP: leaky(agg@W1)@W2 ----------------
__global__ __launch_bounds__(256)
void k_mlp(const float* __restrict__ agg, const float* __restrict__ W1,
           const float* __restrict__ W2, float* __restrict__ xout, int N) {
    __shared__ float sW1[8192];
    __shared__ float sW2[4096];
    __shared__ float sIn[8][128];
    __shared__ float sT[8][64];
    for (int i = threadIdx.x; i < 8192; i += 256) sW1[i] = W1[i];
    for (int i = threadIdx.x; i < 4096; i += 256) sW2[i] = W2[i];
    int w = threadIdx.x >> 6, j = threadIdx.x & 63;
    int ra = 2 * w, rb = ra + 1;
    for (int r0 = blockIdx.x * 8; r0 < N; r0 += gridDim.x * 8) {
        __syncthreads();
        {
            int t = threadIdx.x;
            int rr = t >> 5, c = (t & 31) << 2;
            int r = r0 + rr;
            float4 v = make_float4(0.f, 0.f, 0.f, 0.f);
            if (r < N) v = *reinterpret_cast<const float4*>(&agg[(size_t)r * 128 + c]);
            *reinterpret_cast<float4*>(&sIn[rr][c]) = v;
        }
        __syncthreads();
        float e0 = 0.f, o0 = 0.f, e1 = 0.f, o1 = 0.f;
#pragma unroll
        for (int k = 0; k < 128; k += 4) {
            float4 a = *reinterpret_cast<const float4*>(&sIn[ra][k]);
            float4 b = *reinterpret_cast<const float4*>(&sIn[rb][k]);
            float w0 = sW1[(k + 0) * 64 + j], w1 = sW1[(k + 1) * 64 + j];
            float w2 = sW1[(k + 2) * 64 + j], w3 = sW1[(k + 3) * 64 + j];
            e0 = fmaf(a.x, w0, fmaf(a.z, w2, e0)); o0 = fmaf(a.y, w1, fmaf(a.w, w3, o0));
            e1 = fmaf(b.x, w0, fmaf(b.z, w2, e1)); o1 = fmaf(b.y, w1, fmaf(b.w, w3, o1));
        }
        float acc0 = e0 + o0, acc1 = e1 + o1;
        acc0 = acc0 > 0.f ? acc0 : 0.01f * acc0;
        acc1 = acc1 > 0.f ? acc1 : 0.01f * acc1;
        sT[ra][j] = acc0; sT[rb][j] = acc1;
        __syncthreads();
        e0 = 0.f; o0 = 0.f; e1 = 0.f; o1 = 0.f;
#pragma unroll
        for (int k = 0; k < 64; k += 4) {
            float4 a = *reinterpret_cast<const float4*>(&sT[ra][k]);
            float4 b = *reinterpret_cast<const float4*>(&sT[rb][k]);
            float w0 = sW2[(k + 0) * 64 + j], w1 = sW2[(k + 1) * 64 + j];
            float w2 = sW2[(k + 2) * 64 + j], w3 = sW2[(k + 3) * 64 + j];
            e0 = fmaf(a.x, w0, fmaf(a.z, w2, e0)); o0 = fmaf(a.y, w1, fmaf(a.w, w3, o0));
            e1 = fmaf(b.x, w0, fmaf(b.z, w2, e1)); o1 = fmaf(b.y, w1, fmaf(b.w, w3, o1));
        }
        int r_a = r0 + ra, r_b = r0 + rb;
        if (r_a < N) xout[(size_t)r_a * 64 + j] = e0 + o0;
        if (r_b < N) xout[(size_t)r_b * 64 + j] = e1 + o1;
    }
}

// ---------------- plain GEMM K=64 (GCN sw = s @ Wg) ----------------
__global__ __launch_bounds__(256)
void k_gemm64(const float* __restrict__ in, const float* __restrict__ W,
              float* __restrict__ out, int N) {
    __shared__ float sW[4096];
    __shared__ float sIn[8][64];
    for (int i = threadIdx.x; i < 4096; i += 256) sW[i] = W[i];
    int w = threadIdx.x >> 6, j = threadIdx.x & 63;
    int ra = 2 * w, rb = ra + 1;
    for (int r0 = blockIdx.x * 8; r0 < N; r0 += gridDim.x * 8) {
        __syncthreads();
        if (threadIdx.x < 128) {
            int rr = threadIdx.x >> 4, c = (threadIdx.x & 15) << 2;
            int r = r0 + rr;
            float4 v = make_float4(0.f, 0.f, 0.f, 0.f);
            if (r < N) v = *reinterpret_cast<const float4*>(&in[(size_t)r * 64 + c]);
            *reinterpret_cast<float4*>(&sIn[rr][c]) = v;
        }
        __syncthreads();
        float e0 = 0.f, o0 = 0.f, e1 = 0.f, o1 = 0.f;
#pragma unroll
        for (int k = 0; k < 64; k += 4) {
            float4 a = *reinterpret_cast<const float4*>(&sIn[ra][k]);
            float4 b = *reinterpret_cast<const float4*>(&sIn[rb][k]);
            float w0 = sW[(k + 0) * 64 + j], w1 = sW[(k + 1) * 64 + j];
            float w2 = sW[(k + 2) * 64 + j], w3 = sW[(k + 3) * 64 + j];
            e0 = fmaf(a.x, w0, fmaf(a.z, w2, e0)); o0 = fmaf(a.y, w1, fmaf(a.w, w3, o0));
            e1 = fmaf(b.x, w0, fmaf(b.z, w2, e1)); o1 = fmaf(b.y, w1, fmaf(b.w, w3, o1));
        }
        int r_a = r0 + ra, r_b = r0 + rb;
        if (r_a < N) out[(size_t)r_a * 64 + j] = e0 + o0;
        if (r_b < N) out[(size_t)r_b * 64 + j] = e1 + o1;
    }
}

// ---------------- final GEMM: concat(x_local, s) @ Wh + bh ----------------
__global__ __launch_bounds__(256)
void k_final(const float* __restrict__ A, const float* __restrict__ B,
             const float* __restrict__ Wh, const float* __restrict__ bh,
             float* __restrict__ out, int N) {
    __shared__ float sW[8192];
    __shared__ float sIn[8][128];
    for (int i = threadIdx.x; i < 8192; i += 256) sW[i] = Wh[i];
    int w = threadIdx.x >> 6, j = threadIdx.x & 63;
    int ra = 2 * w, rb = ra + 1;
    float bias = bh[j];
    for (int r0 = blockIdx.x * 8; r0 < N; r0 += gridDim.x * 8) {
        __syncthreads();
        {
            int t = threadIdx.x;
            int rr = t >> 5, c = (t & 31) << 2;
            int r = r0 + rr;
            float4 v = make_float4(0.f, 0.f, 0.f, 0.f);
            if (r < N) {
                v = (c < 64) ? *reinterpret_cast<const float4*>(&A[(size_t)r * 64 + c])
                             : *reinterpret_cast<const float4*>(&B[(size_t)r * 64 + (c - 64)]);
            }
            *reinterpret_cast<float4*>(&sIn[rr][c]) = v;
        }
        __syncthreads();
        float e0 = 0.f, o0 = 0.f, e1 = 0.f, o1 = 0.f;
#pragma unroll
        for (int k = 0; k < 128; k += 4) {
            float4 a = *reinterpret_cast<const float4*>(&sIn[ra][k]);
            float4 b = *reinterpret_cast<const float4*>(&sIn[rb][k]);
            float w0 = sW[(k + 0) * 64 + j], w1 = sW[(k + 1) * 64 + j];
            float w2 = sW[(k + 2) * 64 + j], w3 = sW[(k + 3) * 64 + j];
            e0 = fmaf(a.x, w0, fmaf(a.z, w2, e0)); o0 = fmaf(a.y, w1, fmaf(a.w, w3, o0));
            e1 = fmaf(b.x, w0, fmaf(b.z, w2, e1)); o1 = fmaf(b.y, w1, fmaf(b.w, w3, o1));
        }
        int r_a = r0 + ra, r_b = r0 + rb;
        if (r_a < N) out[(size_t)r_a * 64 + j] = e0 + o0 + bias;
        if (r_b < N) out[(size_t)r_b * 64 + j] = e1 + o1 + bias;
    }
}

// ---------------- BatchNorm (final layer only) ----------------
__global__ __launch_bounds__(256)
void k_bnstats(const float* __restrict__ x, float* __restrict__ stats, int N) {
    __shared__ float ls[4][64], ls2[4][64];
    int w = threadIdx.x >> 6, j = threadIdx.x & 63;
    float s = 0.f, s2 = 0.f;
    for (int r = blockIdx.x * 4 + w; r < N; r += gridDim.x * 4) {
        float v = x[(size_t)r * 64 + j];
        s += v; s2 += v * v;
    }
    ls[w][j] = s; ls2[w][j] = s2;
    __syncthreads();
    if (w == 0) {
        s = ls[0][j] + ls[1][j] + ls[2][j] + ls[3][j];
        s2 = ls2[0][j] + ls2[1][j] + ls2[2][j] + ls2[3][j];
        atomicAdd(&stats[j], s);
        atomicAdd(&stats[64 + j], s2);
    }
}

__global__ void k_bnapply(float* __restrict__ x, const float* __restrict__ stats,
                          const float* __restrict__ gamma, const float* __restrict__ beta,
                          int N) {
    int i = blockIdx.x * 256 + threadIdx.x;
    if (i < N * 64) {
        int j = i & 63;
        float invN = 1.0f / (float)N;
        float mean = stats[j] * invN;
        float var = stats[64 + j] * invN - mean * mean;
        float inv = 1.0f / sqrtf(var + 1e-4f);
        x[i] = gamma[j] * (x[i] - mean) * inv + beta[j];
    }
}

// ---------------- pooling: one block per graph (batch is sorted) ----------------
__global__ __launch_bounds__(256)
void k_pool(const float* __restrict__ out, const int* __restrict__ batch,
            float* __restrict__ pooled, int N) {
    int g = blockIdx.x;
    int lo, hi;
    { int a = 0, b = N; while (a < b) { int m = (a + b) >> 1; if (batch[m] < g) a = m + 1; else b = m; } lo = a; }
    { int a = lo, b = N; while (a < b) { int m = (a + b) >> 1; if (batch[m] < g + 1) a = m + 1; else b = m; } hi = a; }
    int w = threadIdx.x >> 6, j = threadIdx.x & 63;
    float s = 0.f;
    for (int r = lo + w; r < hi; r += 4) s += out[(size_t)r * 64 + j];
    __shared__ float ls[4][64];
    ls[w][j] = s;
    __syncthreads();
    if (w == 0) pooled[g * 64 + j] = ls[0][j] + ls[1][j] + ls[2][j] + ls[3][j];
}

extern "C" void kernel_launch(void* const* d_in, const int* in_sizes, int n_in,
                              void* d_out, int out_size, void* d_ws, size_t ws_size,
                              hipStream_t stream) {
    const float* x_in  = (const float*)d_in[0];
    const float* s_in  = (const float*)d_in[1];
    const float* W1    = (const float*)d_in[2];
    const float* W2    = (const float*)d_in[3];
    const float* gamma = (const float*)d_in[4];
    const float* beta  = (const float*)d_in[5];
    const float* Wg    = (const float*)d_in[6];
    const float* bg    = (const float*)d_in[7];
    const float* Wh    = (const float*)d_in[8];
    const float* bh    = (const float*)d_in[9];
    const int*   ei    = (const int*)d_in[10];
    const int*   batch = (const int*)d_in[11];

    int N = in_sizes[0] / 64;
    int E = in_sizes[10] / 2;
    int L = in_sizes[2] / 8192;
    int G = out_size / 64 - N;

    const int* src = ei;
    const int* dst = ei + E;

    float* pooled = (float*)d_out;
    float* xbuf = pooled + (size_t)G * 64;      // x lives in the x_local output slot; BN is applied in place at the end

    float* ws     = (float*)d_ws;
    float* sbuf   = ws;                          // N*64
    float* agg    = sbuf + (size_t)N * 64;       // N*128 (reused as sw / final out)
    float* dinv   = agg + (size_t)N * 128;       // N
    float* stats  = dinv + N;                    // 128
    int*   rowptr = (int*)(stats + 128);         // N+1
    int*   cntcur = rowptr + (N + 1);            // N
    int*   colsrc = cntcur + N;                  // E
    float* swbuf  = agg;
    float* outbuf = agg;

    hipMemsetAsync(cntcur, 0, (size_t)N * sizeof(int), stream);
    k_hist<<<(E + 255) / 256, 256, 0, stream>>>(dst, cntcur, E);
    k_scan<<<1, 1024, 0, stream>>>(cntcur, rowptr, N);
    k_fill<<<(E + 255) / 256, 256, 0, stream>>>(src, dst, cntcur, colsrc, E);
    k_dinv<<<(N + 255) / 256, 256, 0, stream>>>(rowptr, dinv, N);
    k_copy<<<(N * 16 + 255) / 256, 256, 0, stream>>>((const float4*)x_in, (const float4*)s_in,
                                                     (float4*)xbuf, (float4*)sbuf, N * 16);
    for (int i = 0; i < L; ++i) {
        k_gin_agg<<<N, 64, 0, stream>>>(xbuf, sbuf, rowptr, colsrc, agg, N);
        k_mlp<<<512, 256, 0, stream>>>(agg, W1 + (size_t)i * 8192, W2 + (size_t)i * 4096, xbuf, N);
        k_gemm64<<<512, 256, 0, stream>>>(sbuf, Wg + (size_t)i * 4096, swbuf, N);
        k_gcn_agg<<<N, 64, 0, stream>>>(swbuf, dinv, rowptr, colsrc, bg + (size_t)i * 64, sbuf, N);
    }
    hipMemsetAsync(stats, 0, 128 * sizeof(float), stream);
    k_bnstats<<<256, 256, 0, stream>>>(xbuf, stats, N);
    k_bnapply<<<(N * 64 + 255) / 256, 256, 0, stream>>>(xbuf, stats,
                                                        gamma + (size_t)(L - 1) * 64,
                                                        beta + (size_t)(L - 1) * 64, N);
    k_final<<<512, 256, 0, stream>>>(xbuf, sbuf, Wh, bh, outbuf, N);
    k_pool<<<G, 256, 0, stream>>>(outbuf, batch, pooled, N);
}